// Round 7
// baseline (1690.882 us; speedup 1.0000x reference)
//
#include <hip/hip_runtime.h>

#define NPTS 40000
#define NEDGE 1000000
#define BN_EPS 1e-5f

// ===========================================================================
// Edge geometry: validity + cell + factorized weights.
// ew4 = (wx0, wx1, fy, 0) with wx0=(1-fx)*win, wx1=fx*win.
// Per-cell weight: w(cx,cy) = wxv(cx) * wyv(cy),
//   wxv(ix)=wx0, wxv(ix+1)=wx1, else 0;  wyv(iy)=1-fy, wyv(iy+1)=fy, else 0.
// ===========================================================================
__device__ inline bool edge_geom(const float* rel_pos, const int* ws_ptr, int e,
                                 int& cell, float4& w4) {
    float ws = (float)ws_ptr[0];
    float inv_ws = 1.0f / ws;
    float ux = rel_pos[2 * e] * inv_ws;
    float uy = rel_pos[2 * e + 1] * inv_ws;
    float q = 1.0f - (ux * ux + uy * uy);
    if (!(q > 0.0f)) return false;
    float win = q * q * q;
    float gx = fminf(fmaxf((ux + 1.0f) * 1.5f, 0.0f), 3.0f);
    float gy = fminf(fmaxf((uy + 1.0f) * 1.5f, 0.0f), 3.0f);
    int ix = (int)floorf(gx); ix = ix < 0 ? 0 : (ix > 2 ? 2 : ix);
    int iy = (int)floorf(gy); iy = iy < 0 ? 0 : (iy > 2 ? 2 : iy);
    float fx = gx - (float)ix;
    float fy = gy - (float)iy;
    cell = ix * 4 + iy;
    w4 = make_float4((1.f - fx) * win, fx * win, fy, 0.f);
    return true;
}

__global__ void hist_kernel(const float* __restrict__ rel_pos,
                            const int* __restrict__ receivers,
                            const int* __restrict__ ws_ptr,
                            int* __restrict__ cnt) {
    int e = blockIdx.x * blockDim.x + threadIdx.x;
    if (e >= NEDGE) return;
    int cell; float4 w4;
    if (edge_geom(rel_pos, ws_ptr, e, cell, w4))
        atomicAdd(&cnt[receivers[e]], 1);
}

// one block, 1024 threads: exclusive scan of 40000 counts -> rowptr[40001]
__global__ __launch_bounds__(1024) void scan_kernel(const int* __restrict__ cnt,
                                                    int* __restrict__ rowptr) {
    __shared__ int part[1024];
    int t = threadIdx.x;
    const int CHUNK = 40;  // 1000 threads * 40 = 40000
    int base = t * CHUNK;
    int s = 0;
    if (t < 1000)
        for (int i = 0; i < CHUNK; ++i) s += cnt[base + i];
    part[t] = s;
    __syncthreads();
    for (int off = 1; off < 1024; off <<= 1) {
        int v = (t >= off) ? part[t - off] : 0;
        __syncthreads();
        part[t] += v;
        __syncthreads();
    }
    int excl = (t == 0) ? 0 : part[t - 1];
    if (t < 1000) {
        int run = excl;
        for (int i = 0; i < CHUNK; ++i) { rowptr[base + i] = run; run += cnt[base + i]; }
        if (t == 999) rowptr[NPTS] = run;
    }
}

__global__ void fill_kernel(const float* __restrict__ rel_pos,
                            const int* __restrict__ receivers,
                            const int* __restrict__ senders,
                            const int* __restrict__ ws_ptr,
                            const int* __restrict__ rowptr,
                            int* __restrict__ cursor,
                            int2* __restrict__ sc,
                            float4* __restrict__ ew4) {
    int e = blockIdx.x * blockDim.x + threadIdx.x;
    if (e >= NEDGE) return;
    int cell; float4 w4;
    if (!edge_geom(rel_pos, ws_ptr, e, cell, w4)) return;
    int recv = receivers[e];
    int pos = rowptr[recv] + atomicAdd(&cursor[recv], 1);
    sc[pos] = make_int2(senders[e], cell);
    ew4[pos] = w4;
}

// xa = concat([x, y], axis=-1)  -> [N, 64]
__global__ void build_xa_kernel(const float* __restrict__ x,
                                const float* __restrict__ y,
                                float* __restrict__ xa) {
    int t = blockIdx.x * blockDim.x + threadIdx.x;
    if (t >= NPTS * 64) return;
    int n = t >> 6, c = t & 63;
    xa[t] = (c < 32) ? x[n * 32 + c] : y[n * 32 + (c - 32)];
}

// ===========================================================================
// Per-edge register accumulation. Lane q of a 16-lane slot owns channels
// [q*VEC, q*VEC+VEC) of ALL 16 cells in registers (static indices only).
// ===========================================================================
template <int CIN, int VEC>
__device__ __forceinline__ void do_edge(bool act, int e,
                                        const int2* __restrict__ sc,
                                        const float4* __restrict__ ew4,
                                        const float* __restrict__ feat,
                                        int q, float acc[16][VEC]) {
    int2 rec = sc[e];
    float4 w = ew4[e];
    int sender = act ? rec.x : 0;
    float wx0 = act ? w.x : 0.f;
    float wx1 = act ? w.y : 0.f;
    float fy = w.z;
    int ix = rec.y >> 2, iy = rec.y & 3;
    float wy0 = 1.f - fy, wy1 = fy;
    float wxv[4], wyv[4];
#pragma unroll
    for (int c = 0; c < 4; ++c) {
        wxv[c] = (c == ix) ? wx0 : ((c == ix + 1) ? wx1 : 0.f);
        wyv[c] = (c == iy) ? wy0 : ((c == iy + 1) ? wy1 : 0.f);
    }
    float f[VEC];
    const float* fp = feat + (size_t)sender * CIN + q * VEC;
    if constexpr (VEC == 4) {
        float4 v = *(const float4*)fp;
        f[0] = v.x; f[1] = v.y; f[2] = v.z; f[3] = v.w;
    } else {
        float2 v = *(const float2*)fp;
        f[0] = v.x; f[1] = v.y;
    }
#pragma unroll
    for (int cx = 0; cx < 4; ++cx) {
        float wxc = wxv[cx];
#pragma unroll
        for (int cy = 0; cy < 4; ++cy) {
            float wc = wxc * wyv[cy];
#pragma unroll
            for (int j = 0; j < VEC; ++j)
                acc[cx * 4 + cy][j] = fmaf(wc, f[j], acc[cx * 4 + cy][j]);
        }
    }
}

// ===========================================================================
// Fused cconv layer: 16 receivers per block. Phase 1: register accumulation
// (no LDS RMW, no atomics). Handoff: one ds_write pass. Phase 2: GEMM vs W.
// ===========================================================================
template <int CIN, int COUT>
__global__ __launch_bounds__(256) void fused_layer(const float* __restrict__ feat,
                                                   const int2* __restrict__ sc,
                                                   const float4* __restrict__ ew4,
                                                   const int* __restrict__ rowptr,
                                                   const float* __restrict__ W,
                                                   const float* __restrict__ a,
                                                   float* __restrict__ P) {
    constexpr int RB = 16;            // receivers per block
    constexpr int M = 16 * CIN;       // GEMM K dimension
    constexpr int LDM = M + 4;        // padded row stride
    constexpr int VEC = CIN / 16;     // channels per lane (4 or 2)
    __shared__ float S[RB * LDM];

    int tid = threadIdx.x;
    int lane = tid & 63;
    int wave = tid >> 6;
    int slot = lane >> 4;
    int q = lane & 15;
    int rloc = wave * 4 + slot;
    int rglob = blockIdx.x * RB + rloc;
    int rs = rowptr[rglob];
    int deg = rowptr[rglob + 1] - rs;
    int md = deg;
    md = max(md, __shfl_xor(md, 16));
    md = max(md, __shfl_xor(md, 32));

    float acc[16][VEC];
#pragma unroll
    for (int cc = 0; cc < 16; ++cc)
#pragma unroll
        for (int j = 0; j < VEC; ++j) acc[cc][j] = 0.f;

#pragma unroll 2
    for (int k = 0; k < md; ++k) {
        bool act = k < deg;
        do_edge<CIN, VEC>(act, rs + (act ? k : 0), sc, ew4, feat, q, acc);
    }

    // --- handoff: registers -> LDS (full coverage, no pre-zero needed) ---
    float* srow = &S[rloc * LDM + q * VEC];
#pragma unroll
    for (int cc = 0; cc < 16; ++cc) {
        float* p = srow + cc * CIN;
        if constexpr (VEC == 4)
            *(float4*)p = make_float4(acc[cc][0], acc[cc][1], acc[cc][2], acc[cc][3]);
        else
            *(float2*)p = make_float2(acc[cc][0], acc[cc][1]);
    }
    __syncthreads();

    // --- phase 2: GEMM  P[n][d] = a[n] * sum_m S[n][m] * W[m][d] ---
    constexpr int DVEC = COUT / 16;   // 4 or 2 outputs per thread
    int dq = tid & 15;
    int rg = tid >> 4;
    const float* sr = &S[rg * LDM];
    float racc[DVEC];
#pragma unroll
    for (int t = 0; t < DVEC; ++t) racc[t] = 0.f;

    for (int m = 0; m < M; m += 4) {
        float4 s4 = *(const float4*)&sr[m];
        const float* wp = W + (size_t)m * COUT + dq * DVEC;
#pragma unroll
        for (int j = 0; j < 4; ++j) {
            float sv = (&s4.x)[j];
            if constexpr (DVEC == 4) {
                float4 wv = *(const float4*)(wp + j * COUT);
                racc[0] = fmaf(sv, wv.x, racc[0]);
                racc[1] = fmaf(sv, wv.y, racc[1]);
                racc[2] = fmaf(sv, wv.z, racc[2]);
                racc[3] = fmaf(sv, wv.w, racc[3]);
            } else {
                float2 wv = *(const float2*)(wp + j * COUT);
                racc[0] = fmaf(sv, wv.x, racc[0]);
                racc[1] = fmaf(sv, wv.y, racc[1]);
            }
        }
    }
    int n = blockIdx.x * RB + rg;
    float av = a[n];
#pragma unroll
    for (int t = 0; t < DVEC; ++t)
        P[(size_t)n * COUT + dq * DVEC + t] = av * racc[t];
}

// ===========================================================================
// BatchNorm pieces
// ===========================================================================
template <int COUT>
__global__ void stats_kernel(const float* __restrict__ P, float* __restrict__ st) {
    int d = threadIdx.x;
    float s = 0.f, s2 = 0.f;
    for (int n = blockIdx.x; n < NPTS; n += gridDim.x) {
        float v = P[(size_t)n * COUT + d];
        s += v;
        s2 += v * v;
    }
    atomicAdd(&st[d], s);
    atomicAdd(&st[COUT + d], s2);
}

template <int COUT>
__global__ void finalize_bn_kernel(const float* __restrict__ st,
                                   const float* __restrict__ g,
                                   const float* __restrict__ b,
                                   float* __restrict__ scb) {
    int d = threadIdx.x;
    float mean = st[d] / (float)NPTS;
    float var = st[COUT + d] / (float)NPTS - mean * mean;
    float inv = rsqrtf(var + BN_EPS);
    float scale = inv * g[d];
    scb[d] = scale;
    scb[COUT + d] = b[d] - mean * scale;
}

template <int COUT>
__global__ void apply_relu_kernel(float* __restrict__ P, const float* __restrict__ scb) {
    int t = blockIdx.x * blockDim.x + threadIdx.x;
    if (t >= NPTS * COUT) return;
    int d = t % COUT;
    float v = P[t] * scb[d] + scb[COUT + d];
    P[t] = fmaxf(v, 0.0f);
}

__global__ void apply_sigmix_kernel(const float* __restrict__ P,
                                    const float* __restrict__ scb,
                                    const float* __restrict__ x,
                                    const float* __restrict__ y,
                                    float* __restrict__ out) {
    int t = blockIdx.x * blockDim.x + threadIdx.x;
    if (t >= NPTS * 32) return;
    int d = t & 31;
    float v = P[t] * scb[d] + scb[32 + d];
    float w = 1.0f / (1.0f + expf(-v));
    out[t] = 2.0f * x[t] * w + 2.0f * y[t] * (1.0f - w);
}

// ===========================================================================
template <int CIN, int COUT>
static void run_layer(const float* feat, const int2* sc, const float4* ew4,
                      const int* rowptr, const float* W, const float* g,
                      const float* b, const float* a, float* st, float* scb,
                      float* P, hipStream_t stream) {
    fused_layer<CIN, COUT><<<NPTS / 16, 256, 0, stream>>>(feat, sc, ew4, rowptr, W, a, P);
    hipMemsetAsync(st, 0, 2 * COUT * sizeof(float), stream);
    stats_kernel<COUT><<<128, COUT, 0, stream>>>(P, st);
    finalize_bn_kernel<COUT><<<1, COUT, 0, stream>>>(st, g, b, scb);
}

extern "C" void kernel_launch(void* const* d_in, const int* in_sizes, int n_in,
                              void* d_out, int out_size, void* d_ws, size_t ws_size,
                              hipStream_t stream) {
    const float* x = (const float*)d_in[0];
    const float* y = (const float*)d_in[1];
    const int* senders = (const int*)d_in[2];
    const int* receivers = (const int*)d_in[3];
    const float* rel_pos = (const float*)d_in[4];
    const int* ws_ptr = (const int*)d_in[5];
    const float* a = (const float*)d_in[6];
    const float* W1 = (const float*)d_in[7];
    const float* W2 = (const float*)d_in[8];
    const float* W3 = (const float*)d_in[9];
    const float* W4 = (const float*)d_in[10];
    const float* g1 = (const float*)d_in[11];
    const float* b1 = (const float*)d_in[12];
    const float* g2 = (const float*)d_in[13];
    const float* b2 = (const float*)d_in[14];
    const float* g3 = (const float*)d_in[15];
    const float* b3 = (const float*)d_in[16];
    const float* g4 = (const float*)d_in[17];
    const float* b4 = (const float*)d_in[18];

    char* ws = (char*)d_ws;
    size_t off = 0;
    auto alloc = [&](size_t bytes) -> void* {
        void* p = ws + off;
        off += (bytes + 255) & ~(size_t)255;
        return p;
    };
    int* cnt = (int*)alloc((size_t)NPTS * sizeof(int));
    int* rowptr = (int*)alloc((size_t)(NPTS + 1) * sizeof(int));
    int* cursor = (int*)alloc((size_t)NPTS * sizeof(int));
    int2* sc = (int2*)alloc((size_t)(NEDGE + 4) * sizeof(int2));
    float4* ew4 = (float4*)alloc((size_t)(NEDGE + 4) * sizeof(float4));
    float* xa = (float*)alloc((size_t)NPTS * 64 * sizeof(float));  // also P3
    float* P1 = (float*)alloc((size_t)NPTS * 64 * sizeof(float));
    float* P2 = (float*)alloc((size_t)NPTS * 32 * sizeof(float));  // also P4
    float* xo = (float*)alloc((size_t)NPTS * 32 * sizeof(float));
    float* st = (float*)alloc(2 * 64 * sizeof(float));
    float* scb = (float*)alloc(2 * 64 * sizeof(float));
    (void)ws_size; (void)in_sizes; (void)n_in; (void)out_size;

    // --- CSR build (shared by all 4 layers) ---
    hipMemsetAsync(cnt, 0, (size_t)NPTS * sizeof(int), stream);
    hist_kernel<<<(NEDGE + 255) / 256, 256, 0, stream>>>(rel_pos, receivers, ws_ptr, cnt);
    scan_kernel<<<1, 1024, 0, stream>>>(cnt, rowptr);
    hipMemsetAsync(cursor, 0, (size_t)NPTS * sizeof(int), stream);
    fill_kernel<<<(NEDGE + 255) / 256, 256, 0, stream>>>(rel_pos, receivers, senders, ws_ptr,
                                                         rowptr, cursor, sc, ew4);
    build_xa_kernel<<<(NPTS * 64 + 255) / 256, 256, 0, stream>>>(x, y, xa);

    // Layer 1: cconv(xa; W1) -> P1, relu(bn) in place
    run_layer<64, 64>(xa, sc, ew4, rowptr, W1, g1, b1, a, st, scb, P1, stream);
    apply_relu_kernel<64><<<(NPTS * 64 + 255) / 256, 256, 0, stream>>>(P1, scb);

    // Layer 2: cconv(P1; W2) -> P2, sigmoid-mix -> xo
    run_layer<64, 32>(P1, sc, ew4, rowptr, W2, g2, b2, a, st, scb, P2, stream);
    apply_sigmix_kernel<<<(NPTS * 32 + 255) / 256, 256, 0, stream>>>(P2, scb, x, y, xo);

    // Layer 3: cconv(xo; W3) -> xa (reuse), relu(bn) in place
    run_layer<32, 64>(xo, sc, ew4, rowptr, W3, g3, b3, a, st, scb, xa, stream);
    apply_relu_kernel<64><<<(NPTS * 64 + 255) / 256, 256, 0, stream>>>(xa, scb);

    // Layer 4: cconv(xa; W4) -> P2 (reuse), sigmoid-mix -> out
    run_layer<64, 32>(xa, sc, ew4, rowptr, W4, g4, b4, a, st, scb, P2, stream);
    apply_sigmix_kernel<<<(NPTS * 32 + 255) / 256, 256, 0, stream>>>(P2, scb, x, y, (float*)d_out);
}

// Round 8
// 1049.724 us; speedup vs baseline: 1.6108x; 1.6108x over previous
//
#include <hip/hip_runtime.h>

#define NPTS 40000
#define NEDGE 1000000
#define BN_EPS 1e-5f

// ===========================================================================
// Edge geometry: validity + cell + factorized weights.
// ew4 = (wx0, wx1, fy, 0) with wx0=(1-fx)*win, wx1=fx*win.
// ===========================================================================
__device__ inline bool edge_geom(const float* rel_pos, const int* ws_ptr, int e,
                                 int& cell, float4& w4) {
    float ws = (float)ws_ptr[0];
    float inv_ws = 1.0f / ws;
    float ux = rel_pos[2 * e] * inv_ws;
    float uy = rel_pos[2 * e + 1] * inv_ws;
    float q = 1.0f - (ux * ux + uy * uy);
    if (!(q > 0.0f)) return false;
    float win = q * q * q;
    float gx = fminf(fmaxf((ux + 1.0f) * 1.5f, 0.0f), 3.0f);
    float gy = fminf(fmaxf((uy + 1.0f) * 1.5f, 0.0f), 3.0f);
    int ix = (int)floorf(gx); ix = ix < 0 ? 0 : (ix > 2 ? 2 : ix);
    int iy = (int)floorf(gy); iy = iy < 0 ? 0 : (iy > 2 ? 2 : iy);
    float fx = gx - (float)ix;
    float fy = gy - (float)iy;
    cell = ix * 4 + iy;
    w4 = make_float4((1.f - fx) * win, fx * win, fy, 0.f);
    return true;
}

__global__ void hist_kernel(const float* __restrict__ rel_pos,
                            const int* __restrict__ receivers,
                            const int* __restrict__ ws_ptr,
                            int* __restrict__ cnt) {
    int e = blockIdx.x * blockDim.x + threadIdx.x;
    if (e >= NEDGE) return;
    int cell; float4 w4;
    if (edge_geom(rel_pos, ws_ptr, e, cell, w4))
        atomicAdd(&cnt[receivers[e]], 1);
}

// one block, 1024 threads: exclusive scan of 40000 counts -> rowptr[40001]
__global__ __launch_bounds__(1024) void scan_kernel(const int* __restrict__ cnt,
                                                    int* __restrict__ rowptr) {
    __shared__ int part[1024];
    int t = threadIdx.x;
    const int CHUNK = 40;  // 1000 threads * 40 = 40000
    int base = t * CHUNK;
    int s = 0;
    if (t < 1000)
        for (int i = 0; i < CHUNK; ++i) s += cnt[base + i];
    part[t] = s;
    __syncthreads();
    for (int off = 1; off < 1024; off <<= 1) {
        int v = (t >= off) ? part[t - off] : 0;
        __syncthreads();
        part[t] += v;
        __syncthreads();
    }
    int excl = (t == 0) ? 0 : part[t - 1];
    if (t < 1000) {
        int run = excl;
        for (int i = 0; i < CHUNK; ++i) { rowptr[base + i] = run; run += cnt[base + i]; }
        if (t == 999) rowptr[NPTS] = run;
    }
}

__global__ void fill_kernel(const float* __restrict__ rel_pos,
                            const int* __restrict__ receivers,
                            const int* __restrict__ senders,
                            const int* __restrict__ ws_ptr,
                            const int* __restrict__ rowptr,
                            int* __restrict__ cursor,
                            int2* __restrict__ sc,
                            float4* __restrict__ ew4) {
    int e = blockIdx.x * blockDim.x + threadIdx.x;
    if (e >= NEDGE) return;
    int cell; float4 w4;
    if (!edge_geom(rel_pos, ws_ptr, e, cell, w4)) return;
    int recv = receivers[e];
    int pos = rowptr[recv] + atomicAdd(&cursor[recv], 1);
    sc[pos] = make_int2(senders[e], cell);
    ew4[pos] = w4;
}

// xa = concat([x, y], axis=-1)  -> [N, 64]
__global__ void build_xa_kernel(const float* __restrict__ x,
                                const float* __restrict__ y,
                                float* __restrict__ xa) {
    int t = blockIdx.x * blockDim.x + threadIdx.x;
    if (t >= NPTS * 64) return;
    int n = t >> 6, c = t & 63;
    xa[t] = (c < 32) ? x[n * 32 + c] : y[n * 32 + (c - 32)];
}

// ===========================================================================
// Per-edge register accumulation (unchanged from round 7).
// ===========================================================================
template <int CIN, int VEC>
__device__ __forceinline__ void do_edge(bool act, int e,
                                        const int2* __restrict__ sc,
                                        const float4* __restrict__ ew4,
                                        const float* __restrict__ feat,
                                        int q, float acc[16][VEC]) {
    int2 rec = sc[e];
    float4 w = ew4[e];
    int sender = act ? rec.x : 0;
    float wx0 = act ? w.x : 0.f;
    float wx1 = act ? w.y : 0.f;
    float fy = w.z;
    int ix = rec.y >> 2, iy = rec.y & 3;
    float wy0 = 1.f - fy, wy1 = fy;
    float wxv[4], wyv[4];
#pragma unroll
    for (int c = 0; c < 4; ++c) {
        wxv[c] = (c == ix) ? wx0 : ((c == ix + 1) ? wx1 : 0.f);
        wyv[c] = (c == iy) ? wy0 : ((c == iy + 1) ? wy1 : 0.f);
    }
    float f[VEC];
    const float* fp = feat + (size_t)sender * CIN + q * VEC;
    if constexpr (VEC == 4) {
        float4 v = *(const float4*)fp;
        f[0] = v.x; f[1] = v.y; f[2] = v.z; f[3] = v.w;
    } else {
        float2 v = *(const float2*)fp;
        f[0] = v.x; f[1] = v.y;
    }
#pragma unroll
    for (int cx = 0; cx < 4; ++cx) {
        float wxc = wxv[cx];
#pragma unroll
        for (int cy = 0; cy < 4; ++cy) {
            float wc = wxc * wyv[cy];
#pragma unroll
            for (int j = 0; j < VEC; ++j)
                acc[cx * 4 + cy][j] = fmaf(wc, f[j], acc[cx * 4 + cy][j]);
        }
    }
}

// ===========================================================================
// Fused cconv layer. Phase 1: register accumulation + LDS handoff (as r7).
// Phase 2 (NEW): 4-wave K-split GEMM. Each wave owns M/4 of K; lane
// (rowg,colg) holds a 4xCT register tile; W read ONCE per block from global
// (coalesced float4/float2 per wave-m); S broadcast from LDS. Wave partials
// combined via pair-tree in 8KB LDS scratch.
// ===========================================================================
template <int CIN, int COUT>
__global__ __launch_bounds__(256) void fused_layer(const float* __restrict__ feat,
                                                   const int2* __restrict__ sc,
                                                   const float4* __restrict__ ew4,
                                                   const int* __restrict__ rowptr,
                                                   const float* __restrict__ W,
                                                   const float* __restrict__ a,
                                                   float* __restrict__ P) {
    constexpr int RB = 16;            // receivers per block
    constexpr int M = 16 * CIN;       // GEMM K dimension
    constexpr int LDM = M + 4;        // padded row stride
    constexpr int VEC = CIN / 16;     // channels per lane (4 or 2)
    constexpr int KSL = M / 4;        // K-slice per wave
    constexpr int CT = COUT / 16;     // cols per lane tile (4 or 2)
    __shared__ float S[RB * LDM];
    __shared__ float R[2 * 16 * COUT];  // pair-reduction scratch

    int tid = threadIdx.x;
    int lane = tid & 63;
    int wave = tid >> 6;
    int slot = lane >> 4;
    int q = lane & 15;
    int rloc = wave * 4 + slot;
    int rglob = blockIdx.x * RB + rloc;
    int rs = rowptr[rglob];
    int deg = rowptr[rglob + 1] - rs;
    int md = deg;
    md = max(md, __shfl_xor(md, 16));
    md = max(md, __shfl_xor(md, 32));

    float acc[16][VEC];
#pragma unroll
    for (int cc = 0; cc < 16; ++cc)
#pragma unroll
        for (int j = 0; j < VEC; ++j) acc[cc][j] = 0.f;

#pragma unroll 2
    for (int k = 0; k < md; ++k) {
        bool act = k < deg;
        do_edge<CIN, VEC>(act, rs + (act ? k : 0), sc, ew4, feat, q, acc);
    }

    // --- handoff: registers -> LDS ---
    float* srow = &S[rloc * LDM + q * VEC];
#pragma unroll
    for (int cc = 0; cc < 16; ++cc) {
        float* p = srow + cc * CIN;
        if constexpr (VEC == 4)
            *(float4*)p = make_float4(acc[cc][0], acc[cc][1], acc[cc][2], acc[cc][3]);
        else
            *(float2*)p = make_float2(acc[cc][0], acc[cc][1]);
    }
    __syncthreads();

    // --- phase 2: K-split GEMM ---
    int rowg = (tid >> 4) & 3;        // 4 row-groups (4 rows each)
    int colg = tid & 15;              // 16 col-groups (CT cols each)
    float racc[4][CT];
#pragma unroll
    for (int i = 0; i < 4; ++i)
#pragma unroll
        for (int j = 0; j < CT; ++j) racc[i][j] = 0.f;

    const float* wp0 = W + (size_t)wave * KSL * COUT + colg * CT;
    int mbase = wave * KSL;
#pragma unroll 2
    for (int mm = 0; mm < KSL; ++mm) {
        float wreg[CT];
        if constexpr (CT == 4) {
            float4 w4 = *(const float4*)(wp0 + (size_t)mm * COUT);
            wreg[0] = w4.x; wreg[1] = w4.y; wreg[2] = w4.z; wreg[3] = w4.w;
        } else {
            float2 w2 = *(const float2*)(wp0 + (size_t)mm * COUT);
            wreg[0] = w2.x; wreg[1] = w2.y;
        }
        int m = mbase + mm;
        float s0 = S[(rowg * 4 + 0) * LDM + m];
        float s1 = S[(rowg * 4 + 1) * LDM + m];
        float s2 = S[(rowg * 4 + 2) * LDM + m];
        float s3 = S[(rowg * 4 + 3) * LDM + m];
#pragma unroll
        for (int j = 0; j < CT; ++j) {
            racc[0][j] = fmaf(s0, wreg[j], racc[0][j]);
            racc[1][j] = fmaf(s1, wreg[j], racc[1][j]);
            racc[2][j] = fmaf(s2, wreg[j], racc[2][j]);
            racc[3][j] = fmaf(s3, wreg[j], racc[3][j]);
        }
    }

    // --- pair-tree reduction: (w0+=w1), (w2+=w3), then w0 += w2 ---
    if (wave == 1 || wave == 3) {
        float* r = &R[(wave >> 1) * 16 * COUT];
#pragma unroll
        for (int i = 0; i < 4; ++i) {
            float* p = r + (rowg * 4 + i) * COUT + colg * CT;
            if constexpr (CT == 4)
                *(float4*)p = make_float4(racc[i][0], racc[i][1], racc[i][2], racc[i][3]);
            else
                *(float2*)p = make_float2(racc[i][0], racc[i][1]);
        }
    }
    __syncthreads();
    if (wave == 0 || wave == 2) {
        const float* r = &R[(wave >> 1) * 16 * COUT];
#pragma unroll
        for (int i = 0; i < 4; ++i)
#pragma unroll
            for (int j = 0; j < CT; ++j)
                racc[i][j] += r[(rowg * 4 + i) * COUT + colg * CT + j];
    }
    __syncthreads();
    if (wave == 2) {
#pragma unroll
        for (int i = 0; i < 4; ++i) {
            float* p = &R[(rowg * 4 + i) * COUT + colg * CT];
            if constexpr (CT == 4)
                *(float4*)p = make_float4(racc[i][0], racc[i][1], racc[i][2], racc[i][3]);
            else
                *(float2*)p = make_float2(racc[i][0], racc[i][1]);
        }
    }
    __syncthreads();
    if (wave == 0) {
#pragma unroll
        for (int i = 0; i < 4; ++i) {
            int n = blockIdx.x * RB + rowg * 4 + i;
            float av = a[n];
            float out[CT];
#pragma unroll
            for (int j = 0; j < CT; ++j)
                out[j] = av * (racc[i][j] + R[(rowg * 4 + i) * COUT + colg * CT + j]);
            float* p = P + (size_t)n * COUT + colg * CT;
            if constexpr (CT == 4)
                *(float4*)p = make_float4(out[0], out[1], out[2], out[3]);
            else
                *(float2*)p = make_float2(out[0], out[1]);
        }
    }
}

// ===========================================================================
// BatchNorm: coalesced two-stage deterministic reduction.
// stats_part: 64 blocks x 256 threads, contiguous rows per block.
// ===========================================================================
template <int COUT>
__global__ __launch_bounds__(256) void stats_part_kernel(const float* __restrict__ P,
                                                         float* __restrict__ part) {
    constexpr int RR = NPTS / 64;        // 625 rows per block
    constexpr int RSTEP = 256 / COUT;    // rows per iteration
    __shared__ float ls[256], ls2[256];
    int tid = threadIdx.x;
    int d = tid % COUT;
    int rr = tid / COUT;
    int n0 = blockIdx.x * RR;
    int n1 = n0 + RR;
    float s = 0.f, s2 = 0.f;
    for (int n = n0 + rr; n < n1; n += RSTEP) {
        float v = P[(size_t)n * COUT + d];
        s += v;
        s2 += v * v;
    }
    ls[tid] = s; ls2[tid] = s2;
    __syncthreads();
    if (tid < COUT) {
        for (int k = 1; k < RSTEP; ++k) {
            s += ls[tid + k * COUT];
            s2 += ls2[tid + k * COUT];
        }
        part[blockIdx.x * 2 * COUT + d] = s;
        part[blockIdx.x * 2 * COUT + COUT + d] = s2;
    }
}

template <int COUT>
__global__ void finalize_bn_kernel(const float* __restrict__ part,
                                   const float* __restrict__ g,
                                   const float* __restrict__ b,
                                   float* __restrict__ scb) {
    int d = threadIdx.x;
    float s = 0.f, s2 = 0.f;
    for (int k = 0; k < 64; ++k) {
        s += part[k * 2 * COUT + d];
        s2 += part[k * 2 * COUT + COUT + d];
    }
    float mean = s / (float)NPTS;
    float var = s2 / (float)NPTS - mean * mean;
    float inv = rsqrtf(var + BN_EPS);
    float scale = inv * g[d];
    scb[d] = scale;
    scb[COUT + d] = b[d] - mean * scale;
}

template <int COUT>
__global__ void apply_relu_kernel(float* __restrict__ P, const float* __restrict__ scb) {
    int t = blockIdx.x * blockDim.x + threadIdx.x;
    if (t >= NPTS * COUT) return;
    int d = t % COUT;
    float v = P[t] * scb[d] + scb[COUT + d];
    P[t] = fmaxf(v, 0.0f);
}

__global__ void apply_sigmix_kernel(const float* __restrict__ P,
                                    const float* __restrict__ scb,
                                    const float* __restrict__ x,
                                    const float* __restrict__ y,
                                    float* __restrict__ out) {
    int t = blockIdx.x * blockDim.x + threadIdx.x;
    if (t >= NPTS * 32) return;
    int d = t & 31;
    float v = P[t] * scb[d] + scb[32 + d];
    float w = 1.0f / (1.0f + expf(-v));
    out[t] = 2.0f * x[t] * w + 2.0f * y[t] * (1.0f - w);
}

// ===========================================================================
template <int CIN, int COUT>
static void run_layer(const float* feat, const int2* sc, const float4* ew4,
                      const int* rowptr, const float* W, const float* g,
                      const float* b, const float* a, float* part, float* scb,
                      float* P, hipStream_t stream) {
    fused_layer<CIN, COUT><<<NPTS / 16, 256, 0, stream>>>(feat, sc, ew4, rowptr, W, a, P);
    stats_part_kernel<COUT><<<64, 256, 0, stream>>>(P, part);
    finalize_bn_kernel<COUT><<<1, COUT, 0, stream>>>(part, g, b, scb);
}

extern "C" void kernel_launch(void* const* d_in, const int* in_sizes, int n_in,
                              void* d_out, int out_size, void* d_ws, size_t ws_size,
                              hipStream_t stream) {
    const float* x = (const float*)d_in[0];
    const float* y = (const float*)d_in[1];
    const int* senders = (const int*)d_in[2];
    const int* receivers = (const int*)d_in[3];
    const float* rel_pos = (const float*)d_in[4];
    const int* ws_ptr = (const int*)d_in[5];
    const float* a = (const float*)d_in[6];
    const float* W1 = (const float*)d_in[7];
    const float* W2 = (const float*)d_in[8];
    const float* W3 = (const float*)d_in[9];
    const float* W4 = (const float*)d_in[10];
    const float* g1 = (const float*)d_in[11];
    const float* b1 = (const float*)d_in[12];
    const float* g2 = (const float*)d_in[13];
    const float* b2 = (const float*)d_in[14];
    const float* g3 = (const float*)d_in[15];
    const float* b3 = (const float*)d_in[16];
    const float* g4 = (const float*)d_in[17];
    const float* b4 = (const float*)d_in[18];

    char* ws = (char*)d_ws;
    size_t off = 0;
    auto alloc = [&](size_t bytes) -> void* {
        void* p = ws + off;
        off += (bytes + 255) & ~(size_t)255;
        return p;
    };
    int* cnt = (int*)alloc((size_t)NPTS * sizeof(int));
    int* rowptr = (int*)alloc((size_t)(NPTS + 1) * sizeof(int));
    int* cursor = (int*)alloc((size_t)NPTS * sizeof(int));
    int2* sc = (int2*)alloc((size_t)(NEDGE + 4) * sizeof(int2));
    float4* ew4 = (float4*)alloc((size_t)(NEDGE + 4) * sizeof(float4));
    float* xa = (float*)alloc((size_t)NPTS * 64 * sizeof(float));  // also P3
    float* P1 = (float*)alloc((size_t)NPTS * 64 * sizeof(float));
    float* P2 = (float*)alloc((size_t)NPTS * 32 * sizeof(float));  // also P4
    float* xo = (float*)alloc((size_t)NPTS * 32 * sizeof(float));
    float* part = (float*)alloc((size_t)64 * 2 * 64 * sizeof(float));
    float* scb = (float*)alloc(2 * 64 * sizeof(float));
    (void)ws_size; (void)in_sizes; (void)n_in; (void)out_size;

    // --- CSR build (shared by all 4 layers) ---
    hipMemsetAsync(cnt, 0, (size_t)NPTS * sizeof(int), stream);
    hist_kernel<<<(NEDGE + 255) / 256, 256, 0, stream>>>(rel_pos, receivers, ws_ptr, cnt);
    scan_kernel<<<1, 1024, 0, stream>>>(cnt, rowptr);
    hipMemsetAsync(cursor, 0, (size_t)NPTS * sizeof(int), stream);
    fill_kernel<<<(NEDGE + 255) / 256, 256, 0, stream>>>(rel_pos, receivers, senders, ws_ptr,
                                                         rowptr, cursor, sc, ew4);
    build_xa_kernel<<<(NPTS * 64 + 255) / 256, 256, 0, stream>>>(x, y, xa);

    // Layer 1: cconv(xa; W1) -> P1, relu(bn) in place
    run_layer<64, 64>(xa, sc, ew4, rowptr, W1, g1, b1, a, part, scb, P1, stream);
    apply_relu_kernel<64><<<(NPTS * 64 + 255) / 256, 256, 0, stream>>>(P1, scb);

    // Layer 2: cconv(P1; W2) -> P2, sigmoid-mix -> xo
    run_layer<64, 32>(P1, sc, ew4, rowptr, W2, g2, b2, a, part, scb, P2, stream);
    apply_sigmix_kernel<<<(NPTS * 32 + 255) / 256, 256, 0, stream>>>(P2, scb, x, y, xo);

    // Layer 3: cconv(xo; W3) -> xa (reuse), relu(bn) in place
    run_layer<32, 64>(xo, sc, ew4, rowptr, W3, g3, b3, a, part, scb, xa, stream);
    apply_relu_kernel<64><<<(NPTS * 64 + 255) / 256, 256, 0, stream>>>(xa, scb);

    // Layer 4: cconv(xa; W4) -> P2 (reuse), sigmoid-mix -> out
    run_layer<64, 32>(xa, sc, ew4, rowptr, W4, g4, b4, a, part, scb, P2, stream);
    apply_sigmix_kernel<<<(NPTS * 32 + 255) / 256, 256, 0, stream>>>(P2, scb, x, y, (float*)d_out);
}

// Round 9
// 789.812 us; speedup vs baseline: 2.1409x; 1.3291x over previous
//
#include <hip/hip_runtime.h>

#define NPTS 40000
#define NEDGE 1000000
#define BN_EPS 1e-5f

// ===========================================================================
// Edge geometry: validity + cell + factorized weights.
// ew4 = (wx0, wx1, fy, 0) with wx0=(1-fx)*win, wx1=fx*win.
// ===========================================================================
__device__ inline bool edge_geom(const float* rel_pos, const int* ws_ptr, int e,
                                 int& cell, float4& w4) {
    float ws = (float)ws_ptr[0];
    float inv_ws = 1.0f / ws;
    float ux = rel_pos[2 * e] * inv_ws;
    float uy = rel_pos[2 * e + 1] * inv_ws;
    float q = 1.0f - (ux * ux + uy * uy);
    if (!(q > 0.0f)) return false;
    float win = q * q * q;
    float gx = fminf(fmaxf((ux + 1.0f) * 1.5f, 0.0f), 3.0f);
    float gy = fminf(fmaxf((uy + 1.0f) * 1.5f, 0.0f), 3.0f);
    int ix = (int)floorf(gx); ix = ix < 0 ? 0 : (ix > 2 ? 2 : ix);
    int iy = (int)floorf(gy); iy = iy < 0 ? 0 : (iy > 2 ? 2 : iy);
    float fx = gx - (float)ix;
    float fy = gy - (float)iy;
    cell = ix * 4 + iy;
    w4 = make_float4((1.f - fx) * win, fx * win, fy, 0.f);
    return true;
}

__global__ void hist_kernel(const float* __restrict__ rel_pos,
                            const int* __restrict__ receivers,
                            const int* __restrict__ ws_ptr,
                            int* __restrict__ cnt) {
    int e = blockIdx.x * blockDim.x + threadIdx.x;
    if (e >= NEDGE) return;
    int cell; float4 w4;
    if (edge_geom(rel_pos, ws_ptr, e, cell, w4))
        atomicAdd(&cnt[receivers[e]], 1);
}

// one block, 1024 threads: exclusive scan of 40000 counts -> rowptr[40001]
__global__ __launch_bounds__(1024) void scan_kernel(const int* __restrict__ cnt,
                                                    int* __restrict__ rowptr) {
    __shared__ int part[1024];
    int t = threadIdx.x;
    const int CHUNK = 40;  // 1000 threads * 40 = 40000
    int base = t * CHUNK;
    int s = 0;
    if (t < 1000)
        for (int i = 0; i < CHUNK; ++i) s += cnt[base + i];
    part[t] = s;
    __syncthreads();
    for (int off = 1; off < 1024; off <<= 1) {
        int v = (t >= off) ? part[t - off] : 0;
        __syncthreads();
        part[t] += v;
        __syncthreads();
    }
    int excl = (t == 0) ? 0 : part[t - 1];
    if (t < 1000) {
        int run = excl;
        for (int i = 0; i < CHUNK; ++i) { rowptr[base + i] = run; run += cnt[base + i]; }
        if (t == 999) rowptr[NPTS] = run;
    }
}

__global__ void fill_kernel(const float* __restrict__ rel_pos,
                            const int* __restrict__ receivers,
                            const int* __restrict__ senders,
                            const int* __restrict__ ws_ptr,
                            const int* __restrict__ rowptr,
                            int* __restrict__ cursor,
                            int2* __restrict__ sc,
                            float4* __restrict__ ew4) {
    int e = blockIdx.x * blockDim.x + threadIdx.x;
    if (e >= NEDGE) return;
    int cell; float4 w4;
    if (!edge_geom(rel_pos, ws_ptr, e, cell, w4)) return;
    int recv = receivers[e];
    int pos = rowptr[recv] + atomicAdd(&cursor[recv], 1);
    sc[pos] = make_int2(senders[e], cell);
    ew4[pos] = w4;
}

// xa = concat([x, y], axis=-1)  -> [N, 64]
__global__ void build_xa_kernel(const float* __restrict__ x,
                                const float* __restrict__ y,
                                float* __restrict__ xa) {
    int t = blockIdx.x * blockDim.x + threadIdx.x;
    if (t >= NPTS * 64) return;
    int n = t >> 6, c = t & 63;
    xa[t] = (c < 32) ? x[n * 32 + c] : y[n * 32 + (c - 32)];
}

// ===========================================================================
// Per-edge register accumulation (unchanged).
// ===========================================================================
template <int CIN, int VEC>
__device__ __forceinline__ void do_edge(bool act, int e,
                                        const int2* __restrict__ sc,
                                        const float4* __restrict__ ew4,
                                        const float* __restrict__ feat,
                                        int q, float acc[16][VEC]) {
    int2 rec = sc[e];
    float4 w = ew4[e];
    int sender = act ? rec.x : 0;
    float wx0 = act ? w.x : 0.f;
    float wx1 = act ? w.y : 0.f;
    float fy = w.z;
    int ix = rec.y >> 2, iy = rec.y & 3;
    float wy0 = 1.f - fy, wy1 = fy;
    float wxv[4], wyv[4];
#pragma unroll
    for (int c = 0; c < 4; ++c) {
        wxv[c] = (c == ix) ? wx0 : ((c == ix + 1) ? wx1 : 0.f);
        wyv[c] = (c == iy) ? wy0 : ((c == iy + 1) ? wy1 : 0.f);
    }
    float f[VEC];
    const float* fp = feat + (size_t)sender * CIN + q * VEC;
    if constexpr (VEC == 4) {
        float4 v = *(const float4*)fp;
        f[0] = v.x; f[1] = v.y; f[2] = v.z; f[3] = v.w;
    } else {
        float2 v = *(const float2*)fp;
        f[0] = v.x; f[1] = v.y;
    }
#pragma unroll
    for (int cx = 0; cx < 4; ++cx) {
        float wxc = wxv[cx];
#pragma unroll
        for (int cy = 0; cy < 4; ++cy) {
            float wc = wxc * wyv[cy];
#pragma unroll
            for (int j = 0; j < VEC; ++j)
                acc[cx * 4 + cy][j] = fmaf(wc, f[j], acc[cx * 4 + cy][j]);
        }
    }
}

// ===========================================================================
// Fused cconv layer. Phase 1: register accumulation + LDS handoff (as r8).
// Phase 2: K-split GEMM, 4-m blocked: per step 4 coalesced W rows + 4
// ds_read_b128 of S, 64 fmas; unroll 2 => 8 W loads in flight (covers L2
// latency with issue work). Pair-tree reduction unchanged.
// ===========================================================================
template <int CIN, int COUT>
__global__ __launch_bounds__(256) void fused_layer(const float* __restrict__ feat,
                                                   const int2* __restrict__ sc,
                                                   const float4* __restrict__ ew4,
                                                   const int* __restrict__ rowptr,
                                                   const float* __restrict__ W,
                                                   const float* __restrict__ a,
                                                   float* __restrict__ P) {
    constexpr int RB = 16;            // receivers per block
    constexpr int M = 16 * CIN;       // GEMM K dimension
    constexpr int LDM = M + 4;        // padded row stride
    constexpr int VEC = CIN / 16;     // channels per lane (4 or 2)
    constexpr int KSL = M / 4;        // K-slice per wave
    constexpr int CT = COUT / 16;     // cols per lane tile (4 or 2)
    __shared__ float S[RB * LDM];
    __shared__ float R[2 * 16 * COUT];  // pair-reduction scratch

    int tid = threadIdx.x;
    int lane = tid & 63;
    int wave = tid >> 6;
    int slot = lane >> 4;
    int q = lane & 15;
    int rloc = wave * 4 + slot;
    int rglob = blockIdx.x * RB + rloc;
    int rs = rowptr[rglob];
    int deg = rowptr[rglob + 1] - rs;
    int md = deg;
    md = max(md, __shfl_xor(md, 16));
    md = max(md, __shfl_xor(md, 32));

    float acc[16][VEC];
#pragma unroll
    for (int cc = 0; cc < 16; ++cc)
#pragma unroll
        for (int j = 0; j < VEC; ++j) acc[cc][j] = 0.f;

#pragma unroll 2
    for (int k = 0; k < md; ++k) {
        bool act = k < deg;
        do_edge<CIN, VEC>(act, rs + (act ? k : 0), sc, ew4, feat, q, acc);
    }

    // --- handoff: registers -> LDS ---
    float* srow = &S[rloc * LDM + q * VEC];
#pragma unroll
    for (int cc = 0; cc < 16; ++cc) {
        float* p = srow + cc * CIN;
        if constexpr (VEC == 4)
            *(float4*)p = make_float4(acc[cc][0], acc[cc][1], acc[cc][2], acc[cc][3]);
        else
            *(float2*)p = make_float2(acc[cc][0], acc[cc][1]);
    }
    __syncthreads();

    // --- phase 2: K-split GEMM, 4-m blocked ---
    int rowg = (tid >> 4) & 3;        // 4 row-groups (4 rows each)
    int colg = tid & 15;              // 16 col-groups (CT cols each)
    float racc[4][CT];
#pragma unroll
    for (int i = 0; i < 4; ++i)
#pragma unroll
        for (int j = 0; j < CT; ++j) racc[i][j] = 0.f;

    const float* wp0 = W + (size_t)wave * KSL * COUT + colg * CT;
    int mbase = wave * KSL;
#pragma unroll 2
    for (int mm = 0; mm < KSL; mm += 4) {
        float wreg[4][CT];
#pragma unroll
        for (int u = 0; u < 4; ++u) {
            if constexpr (CT == 4) {
                float4 w4 = *(const float4*)(wp0 + (size_t)(mm + u) * COUT);
                wreg[u][0] = w4.x; wreg[u][1] = w4.y; wreg[u][2] = w4.z; wreg[u][3] = w4.w;
            } else {
                float2 w2 = *(const float2*)(wp0 + (size_t)(mm + u) * COUT);
                wreg[u][0] = w2.x; wreg[u][1] = w2.y;
            }
        }
        float4 sv[4];
#pragma unroll
        for (int i = 0; i < 4; ++i)
            sv[i] = *(const float4*)&S[(rowg * 4 + i) * LDM + mbase + mm];
#pragma unroll
        for (int u = 0; u < 4; ++u) {
#pragma unroll
            for (int i = 0; i < 4; ++i) {
                float s = (&sv[i].x)[u];
#pragma unroll
                for (int j = 0; j < CT; ++j)
                    racc[i][j] = fmaf(s, wreg[u][j], racc[i][j]);
            }
        }
    }

    // --- pair-tree reduction: (w0+=w1), (w2+=w3), then w0 += w2 ---
    if (wave == 1 || wave == 3) {
        float* r = &R[(wave >> 1) * 16 * COUT];
#pragma unroll
        for (int i = 0; i < 4; ++i) {
            float* p = r + (rowg * 4 + i) * COUT + colg * CT;
            if constexpr (CT == 4)
                *(float4*)p = make_float4(racc[i][0], racc[i][1], racc[i][2], racc[i][3]);
            else
                *(float2*)p = make_float2(racc[i][0], racc[i][1]);
        }
    }
    __syncthreads();
    if (wave == 0 || wave == 2) {
        const float* r = &R[(wave >> 1) * 16 * COUT];
#pragma unroll
        for (int i = 0; i < 4; ++i)
#pragma unroll
            for (int j = 0; j < CT; ++j)
                racc[i][j] += r[(rowg * 4 + i) * COUT + colg * CT + j];
    }
    __syncthreads();
    if (wave == 2) {
#pragma unroll
        for (int i = 0; i < 4; ++i) {
            float* p = &R[(rowg * 4 + i) * COUT + colg * CT];
            if constexpr (CT == 4)
                *(float4*)p = make_float4(racc[i][0], racc[i][1], racc[i][2], racc[i][3]);
            else
                *(float2*)p = make_float2(racc[i][0], racc[i][1]);
        }
    }
    __syncthreads();
    if (wave == 0) {
#pragma unroll
        for (int i = 0; i < 4; ++i) {
            int n = blockIdx.x * RB + rowg * 4 + i;
            float av = a[n];
            float out[CT];
#pragma unroll
            for (int j = 0; j < CT; ++j)
                out[j] = av * (racc[i][j] + R[(rowg * 4 + i) * COUT + colg * CT + j]);
            float* p = P + (size_t)n * COUT + colg * CT;
            if constexpr (CT == 4)
                *(float4*)p = make_float4(out[0], out[1], out[2], out[3]);
            else
                *(float2*)p = make_float2(out[0], out[1]);
        }
    }
}

// ===========================================================================
// BatchNorm: coalesced two-stage deterministic reduction.
// ===========================================================================
template <int COUT>
__global__ __launch_bounds__(256) void stats_part_kernel(const float* __restrict__ P,
                                                         float* __restrict__ part) {
    constexpr int RR = NPTS / 64;        // 625 rows per block
    constexpr int RSTEP = 256 / COUT;    // rows per iteration
    __shared__ float ls[256], ls2[256];
    int tid = threadIdx.x;
    int d = tid % COUT;
    int rr = tid / COUT;
    int n0 = blockIdx.x * RR;
    int n1 = n0 + RR;
    float s = 0.f, s2 = 0.f;
    for (int n = n0 + rr; n < n1; n += RSTEP) {
        float v = P[(size_t)n * COUT + d];
        s += v;
        s2 += v * v;
    }
    ls[tid] = s; ls2[tid] = s2;
    __syncthreads();
    if (tid < COUT) {
        for (int k = 1; k < RSTEP; ++k) {
            s += ls[tid + k * COUT];
            s2 += ls2[tid + k * COUT];
        }
        part[blockIdx.x * 2 * COUT + d] = s;
        part[blockIdx.x * 2 * COUT + COUT + d] = s2;
    }
}

template <int COUT>
__global__ void finalize_bn_kernel(const float* __restrict__ part,
                                   const float* __restrict__ g,
                                   const float* __restrict__ b,
                                   float* __restrict__ scb) {
    int d = threadIdx.x;
    float s = 0.f, s2 = 0.f;
    for (int k = 0; k < 64; ++k) {
        s += part[k * 2 * COUT + d];
        s2 += part[k * 2 * COUT + COUT + d];
    }
    float mean = s / (float)NPTS;
    float var = s2 / (float)NPTS - mean * mean;
    float inv = rsqrtf(var + BN_EPS);
    float scale = inv * g[d];
    scb[d] = scale;
    scb[COUT + d] = b[d] - mean * scale;
}

template <int COUT>
__global__ void apply_relu_kernel(float* __restrict__ P, const float* __restrict__ scb) {
    int t = blockIdx.x * blockDim.x + threadIdx.x;
    if (t >= NPTS * COUT) return;
    int d = t % COUT;
    float v = P[t] * scb[d] + scb[COUT + d];
    P[t] = fmaxf(v, 0.0f);
}

__global__ void apply_sigmix_kernel(const float* __restrict__ P,
                                    const float* __restrict__ scb,
                                    const float* __restrict__ x,
                                    const float* __restrict__ y,
                                    float* __restrict__ out) {
    int t = blockIdx.x * blockDim.x + threadIdx.x;
    if (t >= NPTS * 32) return;
    int d = t & 31;
    float v = P[t] * scb[d] + scb[32 + d];
    float w = 1.0f / (1.0f + expf(-v));
    out[t] = 2.0f * x[t] * w + 2.0f * y[t] * (1.0f - w);
}

// ===========================================================================
template <int CIN, int COUT>
static void run_layer(const float* feat, const int2* sc, const float4* ew4,
                      const int* rowptr, const float* W, const float* g,
                      const float* b, const float* a, float* part, float* scb,
                      float* P, hipStream_t stream) {
    fused_layer<CIN, COUT><<<NPTS / 16, 256, 0, stream>>>(feat, sc, ew4, rowptr, W, a, P);
    stats_part_kernel<COUT><<<64, 256, 0, stream>>>(P, part);
    finalize_bn_kernel<COUT><<<1, COUT, 0, stream>>>(part, g, b, scb);
}

extern "C" void kernel_launch(void* const* d_in, const int* in_sizes, int n_in,
                              void* d_out, int out_size, void* d_ws, size_t ws_size,
                              hipStream_t stream) {
    const float* x = (const float*)d_in[0];
    const float* y = (const float*)d_in[1];
    const int* senders = (const int*)d_in[2];
    const int* receivers = (const int*)d_in[3];
    const float* rel_pos = (const float*)d_in[4];
    const int* ws_ptr = (const int*)d_in[5];
    const float* a = (const float*)d_in[6];
    const float* W1 = (const float*)d_in[7];
    const float* W2 = (const float*)d_in[8];
    const float* W3 = (const float*)d_in[9];
    const float* W4 = (const float*)d_in[10];
    const float* g1 = (const float*)d_in[11];
    const float* b1 = (const float*)d_in[12];
    const float* g2 = (const float*)d_in[13];
    const float* b2 = (const float*)d_in[14];
    const float* g3 = (const float*)d_in[15];
    const float* b3 = (const float*)d_in[16];
    const float* g4 = (const float*)d_in[17];
    const float* b4 = (const float*)d_in[18];

    char* ws = (char*)d_ws;
    size_t off = 0;
    auto alloc = [&](size_t bytes) -> void* {
        void* p = ws + off;
        off += (bytes + 255) & ~(size_t)255;
        return p;
    };
    int* cnt = (int*)alloc((size_t)NPTS * sizeof(int));
    int* rowptr = (int*)alloc((size_t)(NPTS + 1) * sizeof(int));
    int* cursor = (int*)alloc((size_t)NPTS * sizeof(int));
    int2* sc = (int2*)alloc((size_t)(NEDGE + 4) * sizeof(int2));
    float4* ew4 = (float4*)alloc((size_t)(NEDGE + 4) * sizeof(float4));
    float* xa = (float*)alloc((size_t)NPTS * 64 * sizeof(float));  // also P3
    float* P1 = (float*)alloc((size_t)NPTS * 64 * sizeof(float));
    float* P2 = (float*)alloc((size_t)NPTS * 32 * sizeof(float));  // also P4
    float* xo = (float*)alloc((size_t)NPTS * 32 * sizeof(float));
    float* part = (float*)alloc((size_t)64 * 2 * 64 * sizeof(float));
    float* scb = (float*)alloc(2 * 64 * sizeof(float));
    (void)ws_size; (void)in_sizes; (void)n_in; (void)out_size;

    // --- CSR build (shared by all 4 layers) ---
    hipMemsetAsync(cnt, 0, (size_t)NPTS * sizeof(int), stream);
    hist_kernel<<<(NEDGE + 255) / 256, 256, 0, stream>>>(rel_pos, receivers, ws_ptr, cnt);
    scan_kernel<<<1, 1024, 0, stream>>>(cnt, rowptr);
    hipMemsetAsync(cursor, 0, (size_t)NPTS * sizeof(int), stream);
    fill_kernel<<<(NEDGE + 255) / 256, 256, 0, stream>>>(rel_pos, receivers, senders, ws_ptr,
                                                         rowptr, cursor, sc, ew4);
    build_xa_kernel<<<(NPTS * 64 + 255) / 256, 256, 0, stream>>>(x, y, xa);

    // Layer 1: cconv(xa; W1) -> P1, relu(bn) in place
    run_layer<64, 64>(xa, sc, ew4, rowptr, W1, g1, b1, a, part, scb, P1, stream);
    apply_relu_kernel<64><<<(NPTS * 64 + 255) / 256, 256, 0, stream>>>(P1, scb);

    // Layer 2: cconv(P1; W2) -> P2, sigmoid-mix -> xo
    run_layer<64, 32>(P1, sc, ew4, rowptr, W2, g2, b2, a, part, scb, P2, stream);
    apply_sigmix_kernel<<<(NPTS * 32 + 255) / 256, 256, 0, stream>>>(P2, scb, x, y, xo);

    // Layer 3: cconv(xo; W3) -> xa (reuse), relu(bn) in place
    run_layer<32, 64>(xo, sc, ew4, rowptr, W3, g3, b3, a, part, scb, xa, stream);
    apply_relu_kernel<64><<<(NPTS * 64 + 255) / 256, 256, 0, stream>>>(xa, scb);

    // Layer 4: cconv(xa; W4) -> P2 (reuse), sigmoid-mix -> out
    run_layer<64, 32>(xa, sc, ew4, rowptr, W4, g4, b4, a, part, scb, P2, stream);
    apply_sigmix_kernel<<<(NPTS * 32 + 255) / 256, 256, 0, stream>>>(P2, scb, x, y, (float*)d_out);
}

// Round 10
// 706.572 us; speedup vs baseline: 2.3931x; 1.1178x over previous
//
#include <hip/hip_runtime.h>

#define NPTS 40000
#define NEDGE 1000000
#define BN_EPS 1e-5f

// ===========================================================================
// Edge geometry: validity + cell + factorized weights.
// ew4 = (wx0, wx1, fy, 0) with wx0=(1-fx)*win, wx1=fx*win.
// ===========================================================================
__device__ inline bool edge_geom(const float* rel_pos, const int* ws_ptr, int e,
                                 int& cell, float4& w4) {
    float ws = (float)ws_ptr[0];
    float inv_ws = 1.0f / ws;
    float ux = rel_pos[2 * e] * inv_ws;
    float uy = rel_pos[2 * e + 1] * inv_ws;
    float q = 1.0f - (ux * ux + uy * uy);
    if (!(q > 0.0f)) return false;
    float win = q * q * q;
    float gx = fminf(fmaxf((ux + 1.0f) * 1.5f, 0.0f), 3.0f);
    float gy = fminf(fmaxf((uy + 1.0f) * 1.5f, 0.0f), 3.0f);
    int ix = (int)floorf(gx); ix = ix < 0 ? 0 : (ix > 2 ? 2 : ix);
    int iy = (int)floorf(gy); iy = iy < 0 ? 0 : (iy > 2 ? 2 : iy);
    float fx = gx - (float)ix;
    float fy = gy - (float)iy;
    cell = ix * 4 + iy;
    w4 = make_float4((1.f - fx) * win, fx * win, fy, 0.f);
    return true;
}

__global__ void hist_kernel(const float* __restrict__ rel_pos,
                            const int* __restrict__ receivers,
                            const int* __restrict__ ws_ptr,
                            int* __restrict__ cnt) {
    int e = blockIdx.x * blockDim.x + threadIdx.x;
    if (e >= NEDGE) return;
    int cell; float4 w4;
    if (edge_geom(rel_pos, ws_ptr, e, cell, w4))
        atomicAdd(&cnt[receivers[e]], 1);
}

// one block, 1024 threads: exclusive scan of 40000 counts -> rowptr[40001]
__global__ __launch_bounds__(1024) void scan_kernel(const int* __restrict__ cnt,
                                                    int* __restrict__ rowptr) {
    __shared__ int part[1024];
    int t = threadIdx.x;
    const int CHUNK = 40;  // 1000 threads * 40 = 40000
    int base = t * CHUNK;
    int s = 0;
    if (t < 1000)
        for (int i = 0; i < CHUNK; ++i) s += cnt[base + i];
    part[t] = s;
    __syncthreads();
    for (int off = 1; off < 1024; off <<= 1) {
        int v = (t >= off) ? part[t - off] : 0;
        __syncthreads();
        part[t] += v;
        __syncthreads();
    }
    int excl = (t == 0) ? 0 : part[t - 1];
    if (t < 1000) {
        int run = excl;
        for (int i = 0; i < CHUNK; ++i) { rowptr[base + i] = run; run += cnt[base + i]; }
        if (t == 999) rowptr[NPTS] = run;
    }
}

__global__ void fill_kernel(const float* __restrict__ rel_pos,
                            const int* __restrict__ receivers,
                            const int* __restrict__ senders,
                            const int* __restrict__ ws_ptr,
                            const int* __restrict__ rowptr,
                            int* __restrict__ cursor,
                            int2* __restrict__ sc,
                            float4* __restrict__ ew4) {
    int e = blockIdx.x * blockDim.x + threadIdx.x;
    if (e >= NEDGE) return;
    int cell; float4 w4;
    if (!edge_geom(rel_pos, ws_ptr, e, cell, w4)) return;
    int recv = receivers[e];
    int pos = rowptr[recv] + atomicAdd(&cursor[recv], 1);
    sc[pos] = make_int2(senders[e], cell);
    ew4[pos] = w4;
}

// xa = concat([x, y], axis=-1)  -> [N, 64]
__global__ void build_xa_kernel(const float* __restrict__ x,
                                const float* __restrict__ y,
                                float* __restrict__ xa) {
    int t = blockIdx.x * blockDim.x + threadIdx.x;
    if (t >= NPTS * 64) return;
    int n = t >> 6, c = t & 63;
    xa[t] = (c < 32) ? x[n * 32 + c] : y[n * 32 + (c - 32)];
}

// ===========================================================================
// Per-edge register accumulation (unchanged).
// ===========================================================================
template <int CIN, int VEC>
__device__ __forceinline__ void do_edge(bool act, int e,
                                        const int2* __restrict__ sc,
                                        const float4* __restrict__ ew4,
                                        const float* __restrict__ feat,
                                        int q, float acc[16][VEC]) {
    int2 rec = sc[e];
    float4 w = ew4[e];
    int sender = act ? rec.x : 0;
    float wx0 = act ? w.x : 0.f;
    float wx1 = act ? w.y : 0.f;
    float fy = w.z;
    int ix = rec.y >> 2, iy = rec.y & 3;
    float wy0 = 1.f - fy, wy1 = fy;
    float wxv[4], wyv[4];
#pragma unroll
    for (int c = 0; c < 4; ++c) {
        wxv[c] = (c == ix) ? wx0 : ((c == ix + 1) ? wx1 : 0.f);
        wyv[c] = (c == iy) ? wy0 : ((c == iy + 1) ? wy1 : 0.f);
    }
    float f[VEC];
    const float* fp = feat + (size_t)sender * CIN + q * VEC;
    if constexpr (VEC == 4) {
        float4 v = *(const float4*)fp;
        f[0] = v.x; f[1] = v.y; f[2] = v.z; f[3] = v.w;
    } else {
        float2 v = *(const float2*)fp;
        f[0] = v.x; f[1] = v.y;
    }
#pragma unroll
    for (int cx = 0; cx < 4; ++cx) {
        float wxc = wxv[cx];
#pragma unroll
        for (int cy = 0; cy < 4; ++cy) {
            float wc = wxc * wyv[cy];
#pragma unroll
            for (int j = 0; j < VEC; ++j)
                acc[cx * 4 + cy][j] = fmaf(wc, f[j], acc[cx * 4 + cy][j]);
        }
    }
}

// write cells [P*8, P*8+8) into half-size S (static indices only)
template <int P, int CIN>
__device__ __forceinline__ void write_chunk(float* __restrict__ S,
                                            const float acc[16][CIN / 16],
                                            int rloc, int q) {
    constexpr int VEC = CIN / 16;
    constexpr int LDMH = 8 * CIN + 4;
    float* srow = S + rloc * LDMH + q * VEC;
#pragma unroll
    for (int c = 0; c < 8; ++c) {
        float* p = srow + c * CIN;
        if constexpr (VEC == 4)
            *(float4*)p = make_float4(acc[P * 8 + c][0], acc[P * 8 + c][1],
                                      acc[P * 8 + c][2], acc[P * 8 + c][3]);
        else
            *(float2*)p = make_float2(acc[P * 8 + c][0], acc[P * 8 + c][1]);
    }
}

// K-split GEMM pass over global m in [P*MH, (P+1)*MH); S holds that chunk.
template <int P, int CIN, int COUT>
__device__ __forceinline__ void gemm_pass(const float* __restrict__ W,
                                          const float* __restrict__ S,
                                          int wave, int rowg, int colg,
                                          float racc[4][COUT / 16]) {
    constexpr int MH = 8 * CIN;
    constexpr int LDMH = MH + 4;
    constexpr int KSL2 = MH / 4;      // K-slice per wave per pass
    constexpr int CT = COUT / 16;
    const float* wp = W + (size_t)(P * MH + wave * KSL2) * COUT + colg * CT;
    const int mb = wave * KSL2;
#pragma unroll 2
    for (int mm = 0; mm < KSL2; mm += 4) {
        float wreg[4][CT];
#pragma unroll
        for (int u = 0; u < 4; ++u) {
            if constexpr (CT == 4) {
                float4 w4 = *(const float4*)(wp + (size_t)(mm + u) * COUT);
                wreg[u][0] = w4.x; wreg[u][1] = w4.y; wreg[u][2] = w4.z; wreg[u][3] = w4.w;
            } else {
                float2 w2 = *(const float2*)(wp + (size_t)(mm + u) * COUT);
                wreg[u][0] = w2.x; wreg[u][1] = w2.y;
            }
        }
        float4 sv[4];
#pragma unroll
        for (int i = 0; i < 4; ++i)
            sv[i] = *(const float4*)&S[(rowg * 4 + i) * LDMH + mb + mm];
#pragma unroll
        for (int u = 0; u < 4; ++u) {
#pragma unroll
            for (int i = 0; i < 4; ++i) {
                float s = (&sv[i].x)[u];
#pragma unroll
                for (int j = 0; j < CT; ++j)
                    racc[i][j] = fmaf(s, wreg[u][j], racc[i][j]);
            }
        }
    }
}

// ===========================================================================
// Fused cconv layer. Phase 1: register accumulation. Phase 2: two-chunk
// half-K handoff (upper cells first, freeing their registers) + K-split
// GEMM per chunk; LDS halved (33KB) -> 4 blocks/CU. Pair-tree reduction
// scratch overlays S after its last read.
// ===========================================================================
template <int CIN, int COUT>
__global__ __launch_bounds__(256, 4) void fused_layer(const float* __restrict__ feat,
                                                      const int2* __restrict__ sc,
                                                      const float4* __restrict__ ew4,
                                                      const int* __restrict__ rowptr,
                                                      const float* __restrict__ W,
                                                      const float* __restrict__ a,
                                                      float* __restrict__ P) {
    constexpr int RB = 16;            // receivers per block
    constexpr int MH = 8 * CIN;       // half-K
    constexpr int LDMH = MH + 4;
    constexpr int VEC = CIN / 16;
    constexpr int CT = COUT / 16;
    __shared__ float S[RB * LDMH];    // half-K staging; reused as reduction R

    int tid = threadIdx.x;
    int lane = tid & 63;
    int wave = tid >> 6;
    int slot = lane >> 4;
    int q = lane & 15;
    int rloc = wave * 4 + slot;
    int rglob = blockIdx.x * RB + rloc;
    int rs = rowptr[rglob];
    int deg = rowptr[rglob + 1] - rs;
    int md = deg;
    md = max(md, __shfl_xor(md, 16));
    md = max(md, __shfl_xor(md, 32));

    float acc[16][VEC];
#pragma unroll
    for (int cc = 0; cc < 16; ++cc)
#pragma unroll
        for (int j = 0; j < VEC; ++j) acc[cc][j] = 0.f;

#pragma unroll 2
    for (int k = 0; k < md; ++k) {
        bool act = k < deg;
        do_edge<CIN, VEC>(act, rs + (act ? k : 0), sc, ew4, feat, q, acc);
    }

    int rowg = (tid >> 4) & 3;        // 4 row-groups (4 rows each)
    int colg = tid & 15;              // 16 col-groups (CT cols each)
    float racc[4][CT];
#pragma unroll
    for (int i = 0; i < 4; ++i)
#pragma unroll
        for (int j = 0; j < CT; ++j) racc[i][j] = 0.f;

    // --- chunk 1 (cells 8..15 -> m in [MH, 2*MH)) first: frees acc[8..15] ---
    write_chunk<1, CIN>(S, acc, rloc, q);
    __syncthreads();
    gemm_pass<1, CIN, COUT>(W, S, wave, rowg, colg, racc);
    __syncthreads();
    // --- chunk 0 (cells 0..7 -> m in [0, MH)) ---
    write_chunk<0, CIN>(S, acc, rloc, q);
    __syncthreads();
    gemm_pass<0, CIN, COUT>(W, S, wave, rowg, colg, racc);
    __syncthreads();

    // --- pair-tree reduction in S's space: (w0+=w1), (w2+=w3), w0 += w2 ---
    float* R = S;                     // 2*16*COUT floats <= RB*LDMH
    if (wave == 1 || wave == 3) {
        float* r = &R[(wave >> 1) * 16 * COUT];
#pragma unroll
        for (int i = 0; i < 4; ++i) {
            float* p = r + (rowg * 4 + i) * COUT + colg * CT;
            if constexpr (CT == 4)
                *(float4*)p = make_float4(racc[i][0], racc[i][1], racc[i][2], racc[i][3]);
            else
                *(float2*)p = make_float2(racc[i][0], racc[i][1]);
        }
    }
    __syncthreads();
    if (wave == 0 || wave == 2) {
        const float* r = &R[(wave >> 1) * 16 * COUT];
#pragma unroll
        for (int i = 0; i < 4; ++i)
#pragma unroll
            for (int j = 0; j < CT; ++j)
                racc[i][j] += r[(rowg * 4 + i) * COUT + colg * CT + j];
    }
    __syncthreads();
    if (wave == 2) {
#pragma unroll
        for (int i = 0; i < 4; ++i) {
            float* p = &R[(rowg * 4 + i) * COUT + colg * CT];
            if constexpr (CT == 4)
                *(float4*)p = make_float4(racc[i][0], racc[i][1], racc[i][2], racc[i][3]);
            else
                *(float2*)p = make_float2(racc[i][0], racc[i][1]);
        }
    }
    __syncthreads();
    if (wave == 0) {
#pragma unroll
        for (int i = 0; i < 4; ++i) {
            int n = blockIdx.x * RB + rowg * 4 + i;
            float av = a[n];
            float out[CT];
#pragma unroll
            for (int j = 0; j < CT; ++j)
                out[j] = av * (racc[i][j] + R[(rowg * 4 + i) * COUT + colg * CT + j]);
            float* p = P + (size_t)n * COUT + colg * CT;
            if constexpr (CT == 4)
                *(float4*)p = make_float4(out[0], out[1], out[2], out[3]);
            else
                *(float2*)p = make_float2(out[0], out[1]);
        }
    }
}

// ===========================================================================
// BatchNorm: coalesced two-stage deterministic reduction.
// ===========================================================================
template <int COUT>
__global__ __launch_bounds__(256) void stats_part_kernel(const float* __restrict__ P,
                                                         float* __restrict__ part) {
    constexpr int RR = NPTS / 64;        // 625 rows per block
    constexpr int RSTEP = 256 / COUT;    // rows per iteration
    __shared__ float ls[256], ls2[256];
    int tid = threadIdx.x;
    int d = tid % COUT;
    int rr = tid / COUT;
    int n0 = blockIdx.x * RR;
    int n1 = n0 + RR;
    float s = 0.f, s2 = 0.f;
    for (int n = n0 + rr; n < n1; n += RSTEP) {
        float v = P[(size_t)n * COUT + d];
        s += v;
        s2 += v * v;
    }
    ls[tid] = s; ls2[tid] = s2;
    __syncthreads();
    if (tid < COUT) {
        for (int k = 1; k < RSTEP; ++k) {
            s += ls[tid + k * COUT];
            s2 += ls2[tid + k * COUT];
        }
        part[blockIdx.x * 2 * COUT + d] = s;
        part[blockIdx.x * 2 * COUT + COUT + d] = s2;
    }
}

template <int COUT>
__global__ void finalize_bn_kernel(const float* __restrict__ part,
                                   const float* __restrict__ g,
                                   const float* __restrict__ b,
                                   float* __restrict__ scb) {
    int d = threadIdx.x;
    float s = 0.f, s2 = 0.f;
    for (int k = 0; k < 64; ++k) {
        s += part[k * 2 * COUT + d];
        s2 += part[k * 2 * COUT + COUT + d];
    }
    float mean = s / (float)NPTS;
    float var = s2 / (float)NPTS - mean * mean;
    float inv = rsqrtf(var + BN_EPS);
    float scale = inv * g[d];
    scb[d] = scale;
    scb[COUT + d] = b[d] - mean * scale;
}

template <int COUT>
__global__ void apply_relu_kernel(float* __restrict__ P, const float* __restrict__ scb) {
    int t = blockIdx.x * blockDim.x + threadIdx.x;
    if (t >= NPTS * COUT) return;
    int d = t % COUT;
    float v = P[t] * scb[d] + scb[COUT + d];
    P[t] = fmaxf(v, 0.0f);
}

__global__ void apply_sigmix_kernel(const float* __restrict__ P,
                                    const float* __restrict__ scb,
                                    const float* __restrict__ x,
                                    const float* __restrict__ y,
                                    float* __restrict__ out) {
    int t = blockIdx.x * blockDim.x + threadIdx.x;
    if (t >= NPTS * 32) return;
    int d = t & 31;
    float v = P[t] * scb[d] + scb[32 + d];
    float w = 1.0f / (1.0f + expf(-v));
    out[t] = 2.0f * x[t] * w + 2.0f * y[t] * (1.0f - w);
}

// ===========================================================================
template <int CIN, int COUT>
static void run_layer(const float* feat, const int2* sc, const float4* ew4,
                      const int* rowptr, const float* W, const float* g,
                      const float* b, const float* a, float* part, float* scb,
                      float* P, hipStream_t stream) {
    fused_layer<CIN, COUT><<<NPTS / 16, 256, 0, stream>>>(feat, sc, ew4, rowptr, W, a, P);
    stats_part_kernel<COUT><<<64, 256, 0, stream>>>(P, part);
    finalize_bn_kernel<COUT><<<1, COUT, 0, stream>>>(part, g, b, scb);
}

extern "C" void kernel_launch(void* const* d_in, const int* in_sizes, int n_in,
                              void* d_out, int out_size, void* d_ws, size_t ws_size,
                              hipStream_t stream) {
    const float* x = (const float*)d_in[0];
    const float* y = (const float*)d_in[1];
    const int* senders = (const int*)d_in[2];
    const int* receivers = (const int*)d_in[3];
    const float* rel_pos = (const float*)d_in[4];
    const int* ws_ptr = (const int*)d_in[5];
    const float* a = (const float*)d_in[6];
    const float* W1 = (const float*)d_in[7];
    const float* W2 = (const float*)d_in[8];
    const float* W3 = (const float*)d_in[9];
    const float* W4 = (const float*)d_in[10];
    const float* g1 = (const float*)d_in[11];
    const float* b1 = (const float*)d_in[12];
    const float* g2 = (const float*)d_in[13];
    const float* b2 = (const float*)d_in[14];
    const float* g3 = (const float*)d_in[15];
    const float* b3 = (const float*)d_in[16];
    const float* g4 = (const float*)d_in[17];
    const float* b4 = (const float*)d_in[18];

    char* ws = (char*)d_ws;
    size_t off = 0;
    auto alloc = [&](size_t bytes) -> void* {
        void* p = ws + off;
        off += (bytes + 255) & ~(size_t)255;
        return p;
    };
    int* cnt = (int*)alloc((size_t)NPTS * sizeof(int));
    int* rowptr = (int*)alloc((size_t)(NPTS + 1) * sizeof(int));
    int* cursor = (int*)alloc((size_t)NPTS * sizeof(int));
    int2* sc = (int2*)alloc((size_t)(NEDGE + 4) * sizeof(int2));
    float4* ew4 = (float4*)alloc((size_t)(NEDGE + 4) * sizeof(float4));
    float* xa = (float*)alloc((size_t)NPTS * 64 * sizeof(float));  // also P3
    float* P1 = (float*)alloc((size_t)NPTS * 64 * sizeof(float));
    float* P2 = (float*)alloc((size_t)NPTS * 32 * sizeof(float));  // also P4
    float* xo = (float*)alloc((size_t)NPTS * 32 * sizeof(float));
    float* part = (float*)alloc((size_t)64 * 2 * 64 * sizeof(float));
    float* scb = (float*)alloc(2 * 64 * sizeof(float));
    (void)ws_size; (void)in_sizes; (void)n_in; (void)out_size;

    // --- CSR build (shared by all 4 layers) ---
    hipMemsetAsync(cnt, 0, (size_t)NPTS * sizeof(int), stream);
    hist_kernel<<<(NEDGE + 255) / 256, 256, 0, stream>>>(rel_pos, receivers, ws_ptr, cnt);
    scan_kernel<<<1, 1024, 0, stream>>>(cnt, rowptr);
    hipMemsetAsync(cursor, 0, (size_t)NPTS * sizeof(int), stream);
    fill_kernel<<<(NEDGE + 255) / 256, 256, 0, stream>>>(rel_pos, receivers, senders, ws_ptr,
                                                         rowptr, cursor, sc, ew4);
    build_xa_kernel<<<(NPTS * 64 + 255) / 256, 256, 0, stream>>>(x, y, xa);

    // Layer 1: cconv(xa; W1) -> P1, relu(bn) in place
    run_layer<64, 64>(xa, sc, ew4, rowptr, W1, g1, b1, a, part, scb, P1, stream);
    apply_relu_kernel<64><<<(NPTS * 64 + 255) / 256, 256, 0, stream>>>(P1, scb);

    // Layer 2: cconv(P1; W2) -> P2, sigmoid-mix -> xo
    run_layer<64, 32>(P1, sc, ew4, rowptr, W2, g2, b2, a, part, scb, P2, stream);
    apply_sigmix_kernel<<<(NPTS * 32 + 255) / 256, 256, 0, stream>>>(P2, scb, x, y, xo);

    // Layer 3: cconv(xo; W3) -> xa (reuse), relu(bn) in place
    run_layer<32, 64>(xo, sc, ew4, rowptr, W3, g3, b3, a, part, scb, xa, stream);
    apply_relu_kernel<64><<<(NPTS * 64 + 255) / 256, 256, 0, stream>>>(xa, scb);

    // Layer 4: cconv(xa; W4) -> P2 (reuse), sigmoid-mix -> out
    run_layer<64, 32>(xa, sc, ew4, rowptr, W4, g4, b4, a, part, scb, P2, stream);
    apply_sigmix_kernel<<<(NPTS * 32 + 255) / 256, 256, 0, stream>>>(P2, scb, x, y, (float*)d_out);
}